// Round 5
// baseline (755.667 us; speedup 1.0000x reference)
//
#include <hip/hip_runtime.h>

#define TPB 256

// clang ext_vector types for nontemporal builtins (HIP_vector_type is rejected)
typedef float ntf4 __attribute__((ext_vector_type(4)));
typedef int   nti4 __attribute__((ext_vector_type(4)));

// ---- LDS-binned scatter parameters ----
// Split passes: one histogram per pass -> 20352 floats = 81408 B LDS/block,
// 2 blocks/CU = 32 waves/CU (the empirical per-CU request rate scales with
// resident waves; round 1 @32w sustained 2x the per-CU rate of round 3 @16w).
// NR = ceil(100000/20352) = 5 scans per pass, but each pass streams only
// 8 B/edge (w + one index) -> 2.05 GB total request traffic for both passes.
#define SCAT_TPB 1024
#define S_RANGE  20352
#define SCAT_GRID 510       // NR(5) * M(102), 2 blocks/CU co-resident

__device__ __forceinline__ unsigned xcc_id() {
    unsigned v;
    asm volatile("s_getreg_b32 %0, hwreg(HW_REG_XCC_ID)" : "=s"(v));
    return v & 7u;
}

// replicas: R copies of [out_deg (N) | in_deg (N)] back to back in ws.
// R computed identically on device in every kernel: min(8, ws_floats/(2N)).
__device__ __forceinline__ int calc_R(unsigned long long ws_bytes, int N) {
    unsigned long long ws_floats = ws_bytes / 4ull;
    unsigned long long r = ws_floats / (unsigned long long)(2 * N);
    if (r > 8ull) r = 8ull;
    if (r < 1ull) r = 1ull;
    return (int)r;
}

// ---- kernel 1: zero R*2N floats of replica space ----
__global__ void ewn_zero_kernel(float* __restrict__ ws,
                                const int* __restrict__ pN,
                                unsigned long long ws_bytes) {
    int N = *pN;
    int R = calc_R(ws_bytes, N);
    long long total = (long long)R * 2 * N;
    for (long long i = blockIdx.x * (long long)blockDim.x + threadIdx.x; i < total;
         i += (long long)gridDim.x * blockDim.x) {
        ws[i] = 0.0f;
    }
}

// ---- kernel 2: single-endpoint node-range-partitioned LDS histogram ----
// Launched twice: pass A (idx=src, off=0 -> out_deg), pass B (idx=dst,
// off=N -> in_deg). Block (r,m) scans stripe m, accumulates nodes in
// [r*S_RANGE,(r+1)*S_RANGE) into LDS, flushes with coalesced
// workgroup-scope atomics into the per-XCD replica.
__global__ __launch_bounds__(SCAT_TPB, 8) void ewn_scatter_kernel(
        const float* __restrict__ w,
        const int* __restrict__ idx,
        float* __restrict__ ws,
        const int* __restrict__ pN,
        unsigned long long ws_bytes,
        int E,
        int table_off_is_N) {   // 0 -> out_deg table, 1 -> in_deg table
    __shared__ float h[S_RANGE];

    const int N = *pN;
    const int R = calc_R(ws_bytes, N);

    int NR = (N + S_RANGE - 1) / S_RANGE;   // 5 for N=100K
    if (NR < 1) NR = 1;
    int M = (int)gridDim.x / NR;            // 102 stripes
    if (M < 1) M = 1;

    const int bid = blockIdx.x;
    if (bid >= NR * M) return;
    const int m = bid / NR;                 // stripe index
    const int r = bid % NR;                 // node-range index
    const int lo = r * S_RANGE;

    for (int i = threadIdx.x; i < S_RANGE; i += SCAT_TPB) h[i] = 0.0f;
    __syncthreads();

    // stripe bounds, 4-element aligned so float4/int4 loads stay 16B-aligned
    long long stripe = (((long long)E + M - 1) / M + 3ll) & ~3ll;
    long long jstart = (long long)m * stripe;
    long long jend   = jstart + stripe;
    if (jend > E) jend = E;

    const long long STEP = (long long)SCAT_TPB * 4;

#define EWN_PROC1(wv, sv) do {                                                            \
        int t_;                                                                           \
        t_ = sv.x - lo; if ((unsigned)t_ < (unsigned)S_RANGE) unsafeAtomicAdd(&h[t_], wv.x); \
        t_ = sv.y - lo; if ((unsigned)t_ < (unsigned)S_RANGE) unsafeAtomicAdd(&h[t_], wv.y); \
        t_ = sv.z - lo; if ((unsigned)t_ < (unsigned)S_RANGE) unsafeAtomicAdd(&h[t_], wv.z); \
        t_ = sv.w - lo; if ((unsigned)t_ < (unsigned)S_RANGE) unsafeAtomicAdd(&h[t_], wv.w); \
    } while (0)

    long long j0 = jstart + (long long)threadIdx.x * 4;

    // main loop: 4 independent coalesced batches; loads pinned in a cluster
    // so clang cannot sink them next to their uses (round-4 lesson: VGPR
    // stayed at 52 -> loads were serialized, MLP never materialized).
    for (; j0 + 3 * STEP + 3 < jend; j0 += 4 * STEP) {
        float4 wv0 = *(const float4*)(w + j0);
        int4   sv0 = *(const int4*)(idx + j0);
        float4 wv1 = *(const float4*)(w + j0 + STEP);
        int4   sv1 = *(const int4*)(idx + j0 + STEP);
        float4 wv2 = *(const float4*)(w + j0 + 2 * STEP);
        int4   sv2 = *(const int4*)(idx + j0 + 2 * STEP);
        float4 wv3 = *(const float4*)(w + j0 + 3 * STEP);
        int4   sv3 = *(const int4*)(idx + j0 + 3 * STEP);
        __builtin_amdgcn_sched_barrier(0);  // keep all 8 loads issued up-front
        EWN_PROC1(wv0, sv0);
        EWN_PROC1(wv1, sv1);
        EWN_PROC1(wv2, sv2);
        EWN_PROC1(wv3, sv3);
    }
    for (; j0 + 3 < jend; j0 += STEP) {
        float4 wv = *(const float4*)(w + j0);
        int4   sv = *(const int4*)(idx + j0);
        EWN_PROC1(wv, sv);
    }
    if (j0 < jend) {
        for (long long j = j0; j < jend; ++j) {
            float wj = w[j];
            int t = idx[j] - lo;
            if ((unsigned)t < (unsigned)S_RANGE) unsafeAtomicAdd(&h[t], wj);
        }
    }
#undef EWN_PROC1
    __syncthreads();

    // flush LDS histogram with coalesced atomics into per-XCD replica
    const unsigned xcc = xcc_id();
    int hi = N - lo;
    if (hi > S_RANGE) hi = S_RANGE;

    if (R == 8) {
        float* deg = ws + (unsigned long long)xcc * 2ull * N
                        + (table_off_is_N ? (unsigned long long)N : 0ull);
        for (int i = threadIdx.x; i < hi; i += SCAT_TPB) {
            __hip_atomic_fetch_add(&deg[lo + i], h[i], __ATOMIC_RELAXED, __HIP_MEMORY_SCOPE_WORKGROUP);
        }
    } else {
        float* deg = ws + (unsigned long long)(xcc % (unsigned)R) * 2ull * N
                        + (table_off_is_N ? (unsigned long long)N : 0ull);
        for (int i = threadIdx.x; i < hi; i += SCAT_TPB) {
            atomicAdd(&deg[lo + i], h[i]);
        }
    }
}

// ---- kernel 3: reduce R replicas + rsqrt, result into replica 0 ----
__global__ void ewn_reduce_norm_kernel(float* __restrict__ ws,
                                       const int* __restrict__ pN,
                                       unsigned long long ws_bytes) {
    int N = *pN;
    int R = calc_R(ws_bytes, N);
    long long n2 = 2ll * N;
    for (long long i = blockIdx.x * (long long)blockDim.x + threadIdx.x; i < n2;
         i += (long long)gridDim.x * blockDim.x) {
        float s = 0.0f;
        for (int r = 0; r < R; ++r) s += ws[(long long)r * n2 + i];
        ws[i] = 1.0f / sqrtf(s);   // precise rsqrt to stay under absmax threshold
    }
}

// ---- kernel 4: out[e] = norm_out[src[e]] * norm_in[dst[e]] * w[e] ----
// 2 batch-strided groups/thread; stream loads clustered, then the 8 table
// gathers clustered, before any FMA. VGPR held <=64 (8 waves/SIMD).
__global__ __launch_bounds__(TPB, 8) void ewn_gather_kernel(
        const float* __restrict__ w,
        const int* __restrict__ src,
        const int* __restrict__ dst,
        const float* __restrict__ ws,
        const int* __restrict__ pN,
        float* __restrict__ out,
        int E) {
    const int N = *pN;
    const float* norm_out = ws;
    const float* norm_in  = ws + N;

    const long long tid  = (long long)blockIdx.x * blockDim.x + threadIdx.x;
    const long long half = (long long)gridDim.x * blockDim.x * 4;  // elems per batch sweep
    long long ia = tid * 4;
    long long ib = ia + half;

    if (ib + 3 < E) {
        ntf4 wva = __builtin_nontemporal_load((const ntf4*)(w + ia));
        nti4 sva = __builtin_nontemporal_load((const nti4*)(src + ia));
        nti4 dva = __builtin_nontemporal_load((const nti4*)(dst + ia));
        ntf4 wvb = __builtin_nontemporal_load((const ntf4*)(w + ib));
        nti4 svb = __builtin_nontemporal_load((const nti4*)(src + ib));
        nti4 dvb = __builtin_nontemporal_load((const nti4*)(dst + ib));
        __builtin_amdgcn_sched_barrier(0);  // pin the 6 stream loads up-front
        float sa0 = norm_out[sva.x], sa1 = norm_out[sva.y], sa2 = norm_out[sva.z], sa3 = norm_out[sva.w];
        float da0 = norm_in[dva.x],  da1 = norm_in[dva.y],  da2 = norm_in[dva.z],  da3 = norm_in[dva.w];
        float sb0 = norm_out[svb.x], sb1 = norm_out[svb.y], sb2 = norm_out[svb.z], sb3 = norm_out[svb.w];
        float db0 = norm_in[dvb.x],  db1 = norm_in[dvb.y],  db2 = norm_in[dvb.z],  db3 = norm_in[dvb.w];
        __builtin_amdgcn_sched_barrier(0);  // pin the 16 gathers as a cluster
        ntf4 ova, ovb;
        ova.x = sa0 * da0 * wva.x;
        ova.y = sa1 * da1 * wva.y;
        ova.z = sa2 * da2 * wva.z;
        ova.w = sa3 * da3 * wva.w;
        ovb.x = sb0 * db0 * wvb.x;
        ovb.y = sb1 * db1 * wvb.y;
        ovb.z = sb2 * db2 * wvb.z;
        ovb.w = sb3 * db3 * wvb.w;
        __builtin_nontemporal_store(ova, (ntf4*)(out + ia));
        __builtin_nontemporal_store(ovb, (ntf4*)(out + ib));
    } else {
        for (int b = 0; b < 2; ++b) {
            long long i4 = b ? ib : ia;
            if (i4 + 3 < E) {
                ntf4 wv = __builtin_nontemporal_load((const ntf4*)(w + i4));
                nti4 sv = __builtin_nontemporal_load((const nti4*)(src + i4));
                nti4 dv = __builtin_nontemporal_load((const nti4*)(dst + i4));
                ntf4 ov;
                ov.x = norm_out[sv.x] * norm_in[dv.x] * wv.x;
                ov.y = norm_out[sv.y] * norm_in[dv.y] * wv.y;
                ov.z = norm_out[sv.z] * norm_in[dv.z] * wv.z;
                ov.w = norm_out[sv.w] * norm_in[dv.w] * wv.w;
                __builtin_nontemporal_store(ov, (ntf4*)(out + i4));
            } else if (i4 < E) {
                for (long long j = i4; j < E && j < i4 + 4; ++j) {
                    out[j] = norm_out[src[j]] * norm_in[dst[j]] * w[j];
                }
            }
        }
    }
}

extern "C" void kernel_launch(void* const* d_in, const int* in_sizes, int n_in,
                              void* d_out, int out_size, void* d_ws, size_t ws_size,
                              hipStream_t stream) {
    const float* edge_weight = (const float*)d_in[0];
    const int*   src         = (const int*)d_in[1];
    const int*   dst         = (const int*)d_in[2];
    const int*   pN          = (const int*)d_in[3];  // 1-element device array
    float* out = (float*)d_out;
    const int E = in_sizes[0];
    float* ws = (float*)d_ws;
    unsigned long long wsb = (unsigned long long)ws_size;

    // gather: 8 edges per thread (2 batch-strided groups of 4)
    int nBlocksGather = (int)(((long long)E / 8 + TPB - 1) / TPB);
    if (nBlocksGather < 1) nBlocksGather = 1;

    ewn_zero_kernel<<<1024, TPB, 0, stream>>>(ws, pN, wsb);
    ewn_scatter_kernel<<<SCAT_GRID, SCAT_TPB, 0, stream>>>(edge_weight, src, ws, pN, wsb, E, 0);
    ewn_scatter_kernel<<<SCAT_GRID, SCAT_TPB, 0, stream>>>(edge_weight, dst, ws, pN, wsb, E, 1);
    ewn_reduce_norm_kernel<<<1024, TPB, 0, stream>>>(ws, pN, wsb);
    ewn_gather_kernel<<<nBlocksGather, TPB, 0, stream>>>(edge_weight, src, dst, ws, pN, out, E);
}

// Round 6
// 724.550 us; speedup vs baseline: 1.0429x; 1.0429x over previous
//
#include <hip/hip_runtime.h>

#define TPB 256

// clang ext_vector types for nontemporal builtins (HIP_vector_type is rejected)
typedef float ntf4 __attribute__((ext_vector_type(4)));
typedef int   nti4 __attribute__((ext_vector_type(4)));

// ---- LDS-binned scatter parameters ----
// Split passes (one histogram each -> 81408 B LDS, 2 blocks/CU, 32 waves/CU)
// merged into ONE dispatch: blocks [0,510) do pass A (src -> out_deg),
// blocks [510,1020) do pass B (dst -> in_deg). NR=5 scans per pass.
// Load budget: 2 passes x 5 scans x 6.4M batches x 2 loads = 128M dwordx4;
// at the measured TA ceiling (~1.09 loads/cy/CU @ 32 waves/CU, round 1)
// that's ~190-210 us. Round-5 lesson: NO sched_barrier, NO manual unroll —
// the plain loop is what reached the issue ceiling in round 1 (m141-style
// order-pinning regression confirmed on this kernel).
#define SCAT_TPB 1024
#define S_RANGE  20352
#define SCAT_HALF_GRID 510   // NR(5) * M(102) per pass
#define SCAT_GRID 1020       // both passes in one dispatch

__device__ __forceinline__ unsigned xcc_id() {
    unsigned v;
    asm volatile("s_getreg_b32 %0, hwreg(HW_REG_XCC_ID)" : "=s"(v));
    return v & 7u;
}

// replicas: R copies of [out_deg (N) | in_deg (N)] back to back in ws.
// R computed identically on device in every kernel: min(8, ws_floats/(2N)).
__device__ __forceinline__ int calc_R(unsigned long long ws_bytes, int N) {
    unsigned long long ws_floats = ws_bytes / 4ull;
    unsigned long long r = ws_floats / (unsigned long long)(2 * N);
    if (r > 8ull) r = 8ull;
    if (r < 1ull) r = 1ull;
    return (int)r;
}

// ---- kernel 1: zero R*2N floats of replica space ----
__global__ void ewn_zero_kernel(float* __restrict__ ws,
                                const int* __restrict__ pN,
                                unsigned long long ws_bytes) {
    int N = *pN;
    int R = calc_R(ws_bytes, N);
    long long total = (long long)R * 2 * N;
    for (long long i = blockIdx.x * (long long)blockDim.x + threadIdx.x; i < total;
         i += (long long)gridDim.x * blockDim.x) {
        ws[i] = 0.0f;
    }
}

// ---- kernel 2: both single-endpoint histogram passes in one dispatch ----
// Block (pass, r, m) scans stripe m of the edge list, accumulates nodes in
// [r*S_RANGE,(r+1)*S_RANGE) of the pass's endpoint into LDS, then flushes
// with coalesced workgroup-scope atomics into the per-XCD replica.
__global__ __launch_bounds__(SCAT_TPB, 8) void ewn_scatter_kernel(
        const float* __restrict__ w,
        const int* __restrict__ src,
        const int* __restrict__ dst,
        float* __restrict__ ws,
        const int* __restrict__ pN,
        unsigned long long ws_bytes,
        int E) {
    __shared__ float h[S_RANGE];

    const int N = *pN;
    const int R = calc_R(ws_bytes, N);

    const int half_grid = (int)gridDim.x / 2;
    const int pass = (blockIdx.x >= half_grid) ? 1 : 0;   // 0: src/out, 1: dst/in
    const int pbid = (int)blockIdx.x - pass * half_grid;
    const int* __restrict__ idx = pass ? dst : src;

    int NR = (N + S_RANGE - 1) / S_RANGE;   // 5 for N=100K
    if (NR < 1) NR = 1;
    int M = half_grid / NR;                 // 102 stripes
    if (M < 1) M = 1;

    if (pbid >= NR * M) return;
    const int m = pbid / NR;                // stripe index
    const int r = pbid % NR;                // node-range index
    const int lo = r * S_RANGE;

    for (int i = threadIdx.x; i < S_RANGE; i += SCAT_TPB) h[i] = 0.0f;
    __syncthreads();

    // stripe bounds, 4-element aligned so float4/int4 loads stay 16B-aligned
    long long stripe = (((long long)E + M - 1) / M + 3ll) & ~3ll;
    long long jstart = (long long)m * stripe;
    long long jend   = jstart + stripe;
    if (jend > E) jend = E;

    const long long STEP = (long long)SCAT_TPB * 4;

    long long j0 = jstart + (long long)threadIdx.x * 4;
    for (; j0 + 3 < jend; j0 += STEP) {
        float4 wv = *(const float4*)(w + j0);
        int4   sv = *(const int4*)(idx + j0);
        int t;
        t = sv.x - lo; if ((unsigned)t < (unsigned)S_RANGE) unsafeAtomicAdd(&h[t], wv.x);
        t = sv.y - lo; if ((unsigned)t < (unsigned)S_RANGE) unsafeAtomicAdd(&h[t], wv.y);
        t = sv.z - lo; if ((unsigned)t < (unsigned)S_RANGE) unsafeAtomicAdd(&h[t], wv.z);
        t = sv.w - lo; if ((unsigned)t < (unsigned)S_RANGE) unsafeAtomicAdd(&h[t], wv.w);
    }
    if (j0 < jend) {
        for (long long j = j0; j < jend; ++j) {
            float wj = w[j];
            int t = idx[j] - lo;
            if ((unsigned)t < (unsigned)S_RANGE) unsafeAtomicAdd(&h[t], wj);
        }
    }
    __syncthreads();

    // flush LDS histogram with coalesced atomics into per-XCD replica
    const unsigned xcc = xcc_id();
    int hi = N - lo;
    if (hi > S_RANGE) hi = S_RANGE;

    if (R == 8) {
        float* deg = ws + (unsigned long long)xcc * 2ull * N
                        + (pass ? (unsigned long long)N : 0ull);
        for (int i = threadIdx.x; i < hi; i += SCAT_TPB) {
            __hip_atomic_fetch_add(&deg[lo + i], h[i], __ATOMIC_RELAXED, __HIP_MEMORY_SCOPE_WORKGROUP);
        }
    } else {
        float* deg = ws + (unsigned long long)(xcc % (unsigned)R) * 2ull * N
                        + (pass ? (unsigned long long)N : 0ull);
        for (int i = threadIdx.x; i < hi; i += SCAT_TPB) {
            atomicAdd(&deg[lo + i], h[i]);
        }
    }
}

// ---- kernel 3: reduce R replicas + rsqrt, result into replica 0 ----
__global__ void ewn_reduce_norm_kernel(float* __restrict__ ws,
                                       const int* __restrict__ pN,
                                       unsigned long long ws_bytes) {
    int N = *pN;
    int R = calc_R(ws_bytes, N);
    long long n2 = 2ll * N;
    for (long long i = blockIdx.x * (long long)blockDim.x + threadIdx.x; i < n2;
         i += (long long)gridDim.x * blockDim.x) {
        float s = 0.0f;
        for (int r = 0; r < R; ++r) s += ws[(long long)r * n2 + i];
        ws[i] = 1.0f / sqrtf(s);   // precise rsqrt to stay under absmax threshold
    }
}

// ---- kernel 4: out[e] = norm_out[src[e]] * norm_in[dst[e]] * w[e] ----
// (unchanged from round 5: 288 -> 220 us) 2 batch-strided groups/thread;
// stream loads clustered, then the 16 table gathers clustered, before any
// FMA. Edge streams non-temporal so the 800 KB norm tables stay L2-resident.
__global__ __launch_bounds__(TPB, 8) void ewn_gather_kernel(
        const float* __restrict__ w,
        const int* __restrict__ src,
        const int* __restrict__ dst,
        const float* __restrict__ ws,
        const int* __restrict__ pN,
        float* __restrict__ out,
        int E) {
    const int N = *pN;
    const float* norm_out = ws;
    const float* norm_in  = ws + N;

    const long long tid  = (long long)blockIdx.x * blockDim.x + threadIdx.x;
    const long long half = (long long)gridDim.x * blockDim.x * 4;  // elems per batch sweep
    long long ia = tid * 4;
    long long ib = ia + half;

    if (ib + 3 < E) {
        ntf4 wva = __builtin_nontemporal_load((const ntf4*)(w + ia));
        nti4 sva = __builtin_nontemporal_load((const nti4*)(src + ia));
        nti4 dva = __builtin_nontemporal_load((const nti4*)(dst + ia));
        ntf4 wvb = __builtin_nontemporal_load((const ntf4*)(w + ib));
        nti4 svb = __builtin_nontemporal_load((const nti4*)(src + ib));
        nti4 dvb = __builtin_nontemporal_load((const nti4*)(dst + ib));
        __builtin_amdgcn_sched_barrier(0);  // pin the 6 stream loads up-front
        float sa0 = norm_out[sva.x], sa1 = norm_out[sva.y], sa2 = norm_out[sva.z], sa3 = norm_out[sva.w];
        float da0 = norm_in[dva.x],  da1 = norm_in[dva.y],  da2 = norm_in[dva.z],  da3 = norm_in[dva.w];
        float sb0 = norm_out[svb.x], sb1 = norm_out[svb.y], sb2 = norm_out[svb.z], sb3 = norm_out[svb.w];
        float db0 = norm_in[dvb.x],  db1 = norm_in[dvb.y],  db2 = norm_in[dvb.z],  db3 = norm_in[dvb.w];
        __builtin_amdgcn_sched_barrier(0);  // pin the 16 gathers as a cluster
        ntf4 ova, ovb;
        ova.x = sa0 * da0 * wva.x;
        ova.y = sa1 * da1 * wva.y;
        ova.z = sa2 * da2 * wva.z;
        ova.w = sa3 * da3 * wva.w;
        ovb.x = sb0 * db0 * wvb.x;
        ovb.y = sb1 * db1 * wvb.y;
        ovb.z = sb2 * db2 * wvb.z;
        ovb.w = sb3 * db3 * wvb.w;
        __builtin_nontemporal_store(ova, (ntf4*)(out + ia));
        __builtin_nontemporal_store(ovb, (ntf4*)(out + ib));
    } else {
        for (int b = 0; b < 2; ++b) {
            long long i4 = b ? ib : ia;
            if (i4 + 3 < E) {
                ntf4 wv = __builtin_nontemporal_load((const ntf4*)(w + i4));
                nti4 sv = __builtin_nontemporal_load((const nti4*)(src + i4));
                nti4 dv = __builtin_nontemporal_load((const nti4*)(dst + i4));
                ntf4 ov;
                ov.x = norm_out[sv.x] * norm_in[dv.x] * wv.x;
                ov.y = norm_out[sv.y] * norm_in[dv.y] * wv.y;
                ov.z = norm_out[sv.z] * norm_in[dv.z] * wv.z;
                ov.w = norm_out[sv.w] * norm_in[dv.w] * wv.w;
                __builtin_nontemporal_store(ov, (ntf4*)(out + i4));
            } else if (i4 < E) {
                for (long long j = i4; j < E && j < i4 + 4; ++j) {
                    out[j] = norm_out[src[j]] * norm_in[dst[j]] * w[j];
                }
            }
        }
    }
}

extern "C" void kernel_launch(void* const* d_in, const int* in_sizes, int n_in,
                              void* d_out, int out_size, void* d_ws, size_t ws_size,
                              hipStream_t stream) {
    const float* edge_weight = (const float*)d_in[0];
    const int*   src         = (const int*)d_in[1];
    const int*   dst         = (const int*)d_in[2];
    const int*   pN          = (const int*)d_in[3];  // 1-element device array
    float* out = (float*)d_out;
    const int E = in_sizes[0];
    float* ws = (float*)d_ws;
    unsigned long long wsb = (unsigned long long)ws_size;

    // gather: 8 edges per thread (2 batch-strided groups of 4)
    int nBlocksGather = (int)(((long long)E / 8 + TPB - 1) / TPB);
    if (nBlocksGather < 1) nBlocksGather = 1;

    ewn_zero_kernel<<<1024, TPB, 0, stream>>>(ws, pN, wsb);
    ewn_scatter_kernel<<<SCAT_GRID, SCAT_TPB, 0, stream>>>(edge_weight, src, dst, ws, pN, wsb, E);
    ewn_reduce_norm_kernel<<<1024, TPB, 0, stream>>>(ws, pN, wsb);
    ewn_gather_kernel<<<nBlocksGather, TPB, 0, stream>>>(edge_weight, src, dst, ws, pN, out, E);
}